// Round 5
// baseline (967.949 us; speedup 1.0000x reference)
//
#include <hip/hip_runtime.h>
#include <math.h>

#define BB 4
#define SS 2048
#define NN 4096
#define DD 256
#define ROWS (BB*SS)        // 8192
#define TOPN 5
#define BM 128
#define BN 128
#define BK 64
#define NCB (NN/BN)         // 32 column blocks
#define PVSTRIDE (NCB*TOPN) // 160
#define NCAND 16
#define ABL_REP 8

typedef short bf16x8 __attribute__((ext_vector_type(8)));
typedef float f32x4  __attribute__((ext_vector_type(4)));
typedef unsigned short u16x4 __attribute__((ext_vector_type(4)));

__device__ inline unsigned short f2bf(float f) {
    unsigned int u = __float_as_uint(f);
    unsigned int r = u + 0x7fffu + ((u >> 16) & 1u);   // RNE
    return (unsigned short)(r >> 16);
}

// HBM -> LDS direct, 16 B per lane. LDS dest is wave-uniform base + lane*16.
__device__ inline void gload_lds16(const void* g, void* l) {
    __builtin_amdgcn_global_load_lds(
        (const __attribute__((address_space(1))) unsigned int*)g,
        (__attribute__((address_space(3))) unsigned int*)l, 16, 0, 0);
}

// sorted-5 insert, strict < keeps earlier (smaller col) on ties
__device__ inline void ins5(float v, int gi,
                            float& b0, float& b1, float& b2, float& b3, float& b4,
                            int& i0, int& i1, int& i2, int& i3, int& i4) {
    if (v < b4) {
        if (v < b3) { b4 = b3; i4 = i3;
            if (v < b2) { b3 = b2; i3 = i2;
                if (v < b1) { b2 = b1; i2 = i1;
                    if (v < b0) { b1 = b0; i1 = i0; b0 = v; i0 = gi; }
                    else        { b1 = v;  i1 = gi; }
                } else { b2 = v; i2 = gi; }
            } else { b3 = v; i3 = gi; }
        } else { b4 = v; i4 = gi; }
    }
}

// ---------------- K1: qp = q @ Wq^T + bq, fp64 accumulate; writes fp64+bf16
__global__ __launch_bounds__(256) void k_proj64(
    const float* __restrict__ q, const float* __restrict__ Wq,
    const float* __restrict__ bq, double* __restrict__ qp64,
    unsigned short* __restrict__ qpb)
{
    __shared__ float As[64][65];
    __shared__ float Bs[64][65];
    const int rowbase = blockIdx.x * 64;
    const int ebase   = blockIdx.y * 64;
    const int t  = threadIdx.x;
    const int tx = t & 15;
    const int ty = t >> 4;

    double acc[4][4];
    #pragma unroll
    for (int i = 0; i < 4; ++i)
        #pragma unroll
        for (int j = 0; j < 4; ++j) acc[i][j] = 0.0;

    for (int k0 = 0; k0 < DD; k0 += 64) {
        #pragma unroll
        for (int i = 0; i < 4; ++i) {
            int r = ty + (i << 4);
            float4 va = *(const float4*)(q  + (size_t)(rowbase + r) * DD + k0 + (tx << 2));
            As[(tx<<2)+0][r] = va.x; As[(tx<<2)+1][r] = va.y;
            As[(tx<<2)+2][r] = va.z; As[(tx<<2)+3][r] = va.w;
            float4 vb = *(const float4*)(Wq + (size_t)(ebase + r) * DD + k0 + (tx << 2));
            Bs[(tx<<2)+0][r] = vb.x; Bs[(tx<<2)+1][r] = vb.y;
            Bs[(tx<<2)+2][r] = vb.z; Bs[(tx<<2)+3][r] = vb.w;
        }
        __syncthreads();
        #pragma unroll 4
        for (int kk = 0; kk < 64; ++kk) {
            double a[4], bb[4];
            #pragma unroll
            for (int i = 0; i < 4; ++i) a[i]  = (double)As[kk][(ty<<2)+i];
            #pragma unroll
            for (int j = 0; j < 4; ++j) bb[j] = (double)Bs[kk][(tx<<2)+j];
            #pragma unroll
            for (int i = 0; i < 4; ++i)
                #pragma unroll
                for (int j = 0; j < 4; ++j)
                    acc[i][j] = fma(a[i], bb[j], acc[i][j]);
        }
        __syncthreads();
    }
    #pragma unroll
    for (int i = 0; i < 4; ++i) {
        int row = rowbase + (ty << 2) + i;
        #pragma unroll
        for (int j = 0; j < 4; ++j) {
            int e = ebase + (tx << 2) + j;
            double r = acc[i][j] + (double)bq[e];
            qp64[(size_t)row * DD + e] = r;
            qpb[(size_t)row * DD + e] = f2bf((float)r);
        }
    }
}

// ------- prep ctx/mem: bf16 convert + fp64/fp32 rownorm in ONE pass -------
__global__ __launch_bounds__(256) void k_prep_cm(
    const float* __restrict__ x, unsigned short* __restrict__ xb,
    double* __restrict__ n64, float* __restrict__ n32)
{
    int row  = blockIdx.x * 4 + (threadIdx.x >> 6);
    int lane = threadIdx.x & 63;
    float4 v = *(const float4*)(x + (size_t)row * DD + (lane << 2));
    u16x4 o;
    o[0] = f2bf(v.x); o[1] = f2bf(v.y); o[2] = f2bf(v.z); o[3] = f2bf(v.w);
    *(u16x4*)(xb + (size_t)row * DD + (lane << 2)) = o;
    double s = (double)v.x*(double)v.x + (double)v.y*(double)v.y
             + (double)v.z*(double)v.z + (double)v.w*(double)v.w;
    #pragma unroll
    for (int off = 32; off; off >>= 1) s += __shfl_xor(s, off);
    if (lane == 0) { n64[row] = s; n32[row] = (float)s; }
}

// ------------- rownorm (double input): sum(x^2) in fp64, 1 wave/row -------
__global__ __launch_bounds__(256) void k_rownorm_d(
    const double* __restrict__ x, double* __restrict__ o64,
    float* __restrict__ o32)
{
    int row  = blockIdx.x * 4 + (threadIdx.x >> 6);
    int lane = threadIdx.x & 63;
    const double* p = x + (size_t)row * DD + (lane << 2);
    double s = p[0]*p[0] + p[1]*p[1] + p[2]*p[2] + p[3]*p[3];
    #pragma unroll
    for (int off = 32; off; off >>= 1) s += __shfl_xor(s, off);
    if (lane == 0) { o64[row] = s; o32[row] = (float)s; }
}

// ------------- gate: sigmoid(q . wg + bg) in fp64, 1 wave/row -------------
__global__ __launch_bounds__(256) void k_gate(
    const float* __restrict__ q, const float* __restrict__ wg,
    const float* __restrict__ bg, double* __restrict__ g64,
    float* __restrict__ g32)
{
    int row  = blockIdx.x * 4 + (threadIdx.x >> 6);
    int lane = threadIdx.x & 63;
    float4 v = *(const float4*)(q  + (size_t)row * DD + (lane << 2));
    float4 w = *(const float4*)(wg + (lane << 2));
    double s = (double)v.x*(double)w.x + (double)v.y*(double)w.y
             + (double)v.z*(double)w.z + (double)v.w*(double)w.w;
    #pragma unroll
    for (int off = 32; off; off >>= 1) s += __shfl_xor(s, off);
    if (lane == 0) {
        double g = 1.0 / (1.0 + exp(-(s + (double)bg[0])));
        g64[row] = g; g32[row] = (float)g;
    }
}

// ---------------- K3: bf16 MFMA distance filter + per-block top-5 ----------
// m97 structure; __launch_bounds__(256,1): VGPR cap 512 -> no pressure spill.
__global__ __launch_bounds__(256, 1) void k_dist_mfma(
    const unsigned short* __restrict__ qpb,
    const unsigned short* __restrict__ ctxb,
    const unsigned short* __restrict__ memb,
    const float* __restrict__ q2, const float* __restrict__ gate,
    const float* __restrict__ c2c, const float* __restrict__ c2m,
    float* __restrict__ pvals, int* __restrict__ pidx)
{
    __shared__ __attribute__((aligned(16))) char smem[49152];
    const int tid  = threadIdx.x;
    const int lane = tid & 63;
    const int wid  = tid >> 6;
    const int wr   = wid >> 1;       // wave row (0/1) -> 64-row half
    const int wc   = wid & 1;        // wave col (0/1) -> 64-col half
    const int rowbase = blockIdx.x * BM;
    const int colbase = blockIdx.y * BN;
    const int b = rowbase / SS;
    const unsigned short* cb  = ctxb + (size_t)b * NN * DD;
    const unsigned short* mbp = memb + (size_t)b * NN * DD;

    f32x4 accC[4][4], accM[4][4];
    f32x4 zz = {0.f, 0.f, 0.f, 0.f};
    #pragma unroll
    for (int i = 0; i < 4; ++i)
        #pragma unroll
        for (int j = 0; j < 4; ++j) { accC[i][j] = zz; accM[i][j] = zz; }

    for (int t = 0; t < DD / BK; ++t) {
        const int k0 = t * BK;
        __syncthreads();   // previous consume done
        #pragma unroll
        for (int i = 0; i < 4; ++i) {
            int s = i * 256 + tid;
            int r = s >> 3, c = s & 7;
            const unsigned short* ga = qpb + (size_t)(rowbase + r) * DD + k0 + c * 8;
            const unsigned short* gc = cb  + (size_t)(colbase + r) * DD + k0 + c * 8;
            const unsigned short* gm = mbp + (size_t)(colbase + r) * DD + k0 + c * 8;
            char* la = smem +         i * 4096 + wid * 1024;   // wave-uniform
            char* lc = smem + 16384 + i * 4096 + wid * 1024;
            char* lm = smem + 32768 + i * 4096 + wid * 1024;
            gload_lds16(ga, la);
            gload_lds16(gc, lc);
            gload_lds16(gm, lm);
        }
        __syncthreads();   // stage visible
        #pragma unroll
        for (int ks = 0; ks < 2; ++ks) {
            bf16x8 af[4], bcf[4], bmf[4];
            const int koff = (ks * 4 + (lane >> 4)) * 16;   // byte offset in row
            #pragma unroll
            for (int f = 0; f < 4; ++f) {
                int arow = wr * 64 + f * 16 + (lane & 15);
                af[f] = *(const bf16x8*)(smem + arow * 128 + koff);
                int brow = wc * 64 + f * 16 + (lane & 15);
                bcf[f] = *(const bf16x8*)(smem + 16384 + brow * 128 + koff);
                bmf[f] = *(const bf16x8*)(smem + 32768 + brow * 128 + koff);
            }
            #pragma unroll
            for (int mf = 0; mf < 4; ++mf)
                #pragma unroll
                for (int nf = 0; nf < 4; ++nf) {
                    accC[mf][nf] = __builtin_amdgcn_mfma_f32_16x16x32_bf16(
                        af[mf], bcf[nf], accC[mf][nf], 0, 0, 0);
                    accM[mf][nf] = __builtin_amdgcn_mfma_f32_16x16x32_bf16(
                        af[mf], bmf[nf], accM[mf][nf], 0, 0, 0);
                }
        }
    }

    // per-lane row/col metadata (C/D map: row=(lane>>4)*4+reg, col=lane&15)
    float q2r[4][4], gr[4][4];
    #pragma unroll
    for (int mf = 0; mf < 4; ++mf)
        #pragma unroll
        for (int rg = 0; rg < 4; ++rg) {
            int r = rowbase + wr * 64 + mf * 16 + ((lane >> 4) << 2) + rg;
            q2r[mf][rg] = q2[r];
            gr[mf][rg]  = gate[r];
        }
    float ccv[4], cmv[4];
    #pragma unroll
    for (int nf = 0; nf < 4; ++nf) {
        int c = colbase + wc * 64 + nf * 16 + (lane & 15);
        ccv[nf] = c2c[b * NN + c];
        cmv[nf] = c2m[b * NN + c];
    }

    float* distl = (float*)smem;            // [64][129] = 33024 B
    float* pvv   = (float*)(smem + 33024);  // [64][4][5]
    int*   pvi   = (int*)  (smem + 38144);  // [64][4][5]

    #pragma unroll
    for (int p = 0; p < 2; ++p) {
        __syncthreads();   // tiles (or previous phase) dead
        if (wr == p) {
            #pragma unroll
            for (int mf = 0; mf < 4; ++mf)
                #pragma unroll
                for (int nf = 0; nf < 4; ++nf)
                    #pragma unroll
                    for (int rg = 0; rg < 4; ++rg) {
                        int rl = mf * 16 + ((lane >> 4) << 2) + rg;   // 0..63
                        int cl = wc * 64 + nf * 16 + (lane & 15);     // 0..127
                        float g  = gr[mf][rg];
                        float dc = sqrtf(fmaxf(q2r[mf][rg] + ccv[nf]
                                               - 2.0f * accC[mf][nf][rg], 0.f));
                        float dm = sqrtf(fmaxf(q2r[mf][rg] + cmv[nf]
                                               - 2.0f * accM[mf][nf][rg], 0.f));
                        distl[rl * 129 + cl] = g * dc + (1.f - g) * dm;
                    }
        }
        __syncthreads();
        {   // 4 threads per row, 32 cols each
            int r = tid & 63, seg = tid >> 6;
            int cbase = seg * 32;
            float b0 = INFINITY, b1 = INFINITY, b2 = INFINITY, b3 = INFINITY, b4 = INFINITY;
            int   i0 = 0x7fffffff, i1 = 0x7fffffff, i2 = 0x7fffffff, i3 = 0x7fffffff, i4 = 0x7fffffff;
            for (int c = 0; c < 32; ++c) {
                float v = distl[r * 129 + cbase + c];
                ins5(v, colbase + cbase + c, b0, b1, b2, b3, b4, i0, i1, i2, i3, i4);
            }
            int pb = (r * 4 + seg) * 5;
            pvv[pb+0] = b0; pvv[pb+1] = b1; pvv[pb+2] = b2; pvv[pb+3] = b3; pvv[pb+4] = b4;
            pvi[pb+0] = i0; pvi[pb+1] = i1; pvi[pb+2] = i2; pvi[pb+3] = i3; pvi[pb+4] = i4;
        }
        __syncthreads();
        if (tid < 64) {    // merge 4 sorted-5 lists (seg asc = col asc -> ties OK)
            int r = tid;
            float b0 = INFINITY, b1 = INFINITY, b2 = INFINITY, b3 = INFINITY, b4 = INFINITY;
            int   i0 = 0x7fffffff, i1 = 0x7fffffff, i2 = 0x7fffffff, i3 = 0x7fffffff, i4 = 0x7fffffff;
            #pragma unroll
            for (int sg = 0; sg < 4; ++sg)
                #pragma unroll
                for (int k = 0; k < 5; ++k) {
                    int pb = (r * 4 + sg) * 5 + k;
                    ins5(pvv[pb], pvi[pb], b0, b1, b2, b3, b4, i0, i1, i2, i3, i4);
                }
            int row_g = rowbase + p * 64 + r;
            size_t ob = (size_t)row_g * PVSTRIDE + (size_t)blockIdx.y * TOPN;
            pvals[ob+0] = b0; pvals[ob+1] = b1; pvals[ob+2] = b2;
            pvals[ob+3] = b3; pvals[ob+4] = b4;
            pidx[ob+0] = i0; pidx[ob+1] = i1; pidx[ob+2] = i2;
            pidx[ob+3] = i3; pidx[ob+4] = i4;
        }
    }
}

// ---------------- ABLATION: K-loop only (stage + MFMA), x8, no stores ------
// Readout via total dur_us + top-5 table. Keepalive prevents DCE (rule #17).
__global__ __launch_bounds__(256, 1) void k_abl_kloop(
    const unsigned short* __restrict__ qpb,
    const unsigned short* __restrict__ ctxb,
    const unsigned short* __restrict__ memb)
{
    __shared__ __attribute__((aligned(16))) char smem[49152];
    const int tid  = threadIdx.x;
    const int lane = tid & 63;
    const int wid  = tid >> 6;
    const int wr   = wid >> 1;
    const int wc   = wid & 1;
    const int rowbase = blockIdx.x * BM;
    const int colbase = blockIdx.y * BN;
    const int b = rowbase / SS;
    const unsigned short* cb  = ctxb + (size_t)b * NN * DD;
    const unsigned short* mbp = memb + (size_t)b * NN * DD;

    f32x4 accC[4][4], accM[4][4];
    f32x4 zz = {0.f, 0.f, 0.f, 0.f};
    #pragma unroll
    for (int i = 0; i < 4; ++i)
        #pragma unroll
        for (int j = 0; j < 4; ++j) { accC[i][j] = zz; accM[i][j] = zz; }

    for (int rep = 0; rep < ABL_REP; ++rep) {
        for (int t = 0; t < DD / BK; ++t) {
            const int k0 = t * BK;
            __syncthreads();
            #pragma unroll
            for (int i = 0; i < 4; ++i) {
                int s = i * 256 + tid;
                int r = s >> 3, c = s & 7;
                const unsigned short* ga = qpb + (size_t)(rowbase + r) * DD + k0 + c * 8;
                const unsigned short* gc = cb  + (size_t)(colbase + r) * DD + k0 + c * 8;
                const unsigned short* gm = mbp + (size_t)(colbase + r) * DD + k0 + c * 8;
                gload_lds16(ga, smem +         i * 4096 + wid * 1024);
                gload_lds16(gc, smem + 16384 + i * 4096 + wid * 1024);
                gload_lds16(gm, smem + 32768 + i * 4096 + wid * 1024);
            }
            __syncthreads();
            #pragma unroll
            for (int ks = 0; ks < 2; ++ks) {
                bf16x8 af[4], bcf[4], bmf[4];
                const int koff = (ks * 4 + (lane >> 4)) * 16;
                #pragma unroll
                for (int f = 0; f < 4; ++f) {
                    int arow = wr * 64 + f * 16 + (lane & 15);
                    af[f] = *(const bf16x8*)(smem + arow * 128 + koff);
                    int brow = wc * 64 + f * 16 + (lane & 15);
                    bcf[f] = *(const bf16x8*)(smem + 16384 + brow * 128 + koff);
                    bmf[f] = *(const bf16x8*)(smem + 32768 + brow * 128 + koff);
                }
                #pragma unroll
                for (int mf = 0; mf < 4; ++mf)
                    #pragma unroll
                    for (int nf = 0; nf < 4; ++nf) {
                        accC[mf][nf] = __builtin_amdgcn_mfma_f32_16x16x32_bf16(
                            af[mf], bcf[nf], accC[mf][nf], 0, 0, 0);
                        accM[mf][nf] = __builtin_amdgcn_mfma_f32_16x16x32_bf16(
                            af[mf], bmf[nf], accM[mf][nf], 0, 0, 0);
                    }
            }
        }
    }
    float s = 0.f;
    #pragma unroll
    for (int i = 0; i < 4; ++i)
        #pragma unroll
        for (int j = 0; j < 4; ++j)
            #pragma unroll
            for (int r = 0; r < 4; ++r)
                s += accC[i][j][r] + accM[i][j][r];
    asm volatile("" : : "v"(s));
}

// ---------------- K4: merge 32 partial top-5 lists -> top-16 candidates ---
__global__ __launch_bounds__(256) void k_merge16(
    const float* __restrict__ pvals, const int* __restrict__ pidx,
    int* __restrict__ cand)
{
    int row  = blockIdx.x * 4 + (threadIdx.x >> 6);
    int lane = threadIdx.x & 63;
    float h0 = INFINITY, h1 = INFINITY, h2 = INFINITY, h3 = INFINITY, h4 = INFINITY;
    int   j0 = 0x7fffffff, j1 = 0x7fffffff, j2 = 0x7fffffff, j3 = 0x7fffffff, j4 = 0x7fffffff;
    if (lane < NCB) {
        size_t base = (size_t)row * PVSTRIDE + (size_t)lane * TOPN;
        h0 = pvals[base+0]; h1 = pvals[base+1]; h2 = pvals[base+2];
        h3 = pvals[base+3]; h4 = pvals[base+4];
        j0 = pidx[base+0]; j1 = pidx[base+1]; j2 = pidx[base+2];
        j3 = pidx[base+3]; j4 = pidx[base+4];
    }
    #pragma unroll
    for (int r = 0; r < NCAND; ++r) {
        float mv = h0; int mi = j0;
        #pragma unroll
        for (int off = 1; off < 64; off <<= 1) {
            float ov = __shfl_xor(mv, off);
            int   oi = __shfl_xor(mi, off);
            if (ov < mv || (ov == mv && oi < mi)) { mv = ov; mi = oi; }
        }
        if (h0 == mv && j0 == mi) {
            h0 = h1; j0 = j1; h1 = h2; j1 = j2; h2 = h3; j2 = j3;
            h3 = h4; j3 = j4; h4 = INFINITY; j4 = 0x7fffffff;
        }
        if (lane == 0) cand[(size_t)row * NCAND + r] = mi;
    }
}

// ---------------- K5: fp64 exact rescore of 16 candidates, final top-5 ----
__global__ __launch_bounds__(64) void k_rescore(
    const double* __restrict__ qp64, const float* __restrict__ ctx,
    const float* __restrict__ mem, const double* __restrict__ q2,
    const double* __restrict__ gate, const double* __restrict__ c2c,
    const double* __restrict__ c2m, const int* __restrict__ cand,
    float* __restrict__ out)
{
    __shared__ double sval[NCAND];
    __shared__ int    sidx[NCAND];
    const int row  = blockIdx.x;
    const int lane = threadIdx.x;
    const int b = row / SS;

    const double* qr = qp64 + (size_t)row * DD + (lane << 2);
    double a0 = qr[0], a1 = qr[1], a2 = qr[2], a3 = qr[3];
    double q2r = q2[row], g = gate[row];

    for (int c = 0; c < NCAND; ++c) {
        int idx = cand[(size_t)row * NCAND + c];
        const float4 vc = *(const float4*)(ctx + ((size_t)b * NN + idx) * DD + (lane << 2));
        const float4 vm = *(const float4*)(mem + ((size_t)b * NN + idx) * DD + (lane << 2));
        double sc = a0*(double)vc.x + a1*(double)vc.y + a2*(double)vc.z + a3*(double)vc.w;
        double sm = a0*(double)vm.x + a1*(double)vm.y + a2*(double)vm.z + a3*(double)vm.w;
        #pragma unroll
        for (int off = 32; off; off >>= 1) {
            sc += __shfl_xor(sc, off);
            sm += __shfl_xor(sm, off);
        }
        if (lane == 0) {
            double dc = sqrt(fmax(q2r + c2c[(size_t)b * NN + idx] - 2.0 * sc, 0.0));
            double dm = sqrt(fmax(q2r + c2m[(size_t)b * NN + idx] - 2.0 * sm, 0.0));
            sval[c] = g * dc + (1.0 - g) * dm;
            sidx[c] = idx;
        }
    }
    __syncthreads();
    if (lane == 0) {
        #pragma unroll
        for (int r = 0; r < TOPN; ++r) {
            double bv = sval[0]; int bi = sidx[0]; int bp = 0;
            for (int c = 1; c < NCAND; ++c) {
                double v = sval[c]; int ii = sidx[c];
                if (v < bv || (v == bv && ii < bi)) { bv = v; bi = ii; bp = c; }
            }
            sval[bp] = INFINITY; sidx[bp] = 0x7fffffff;
            out[(size_t)row * TOPN + r] = (float)bv;
            out[(size_t)ROWS * TOPN + (size_t)row * TOPN + r] = (float)bi;
        }
    }
}

extern "C" void kernel_launch(void* const* d_in, const int* in_sizes, int n_in,
                              void* d_out, int out_size, void* d_ws, size_t ws_size,
                              hipStream_t stream)
{
    const float* q   = (const float*)d_in[0];
    const float* ctx = (const float*)d_in[1];
    const float* mem = (const float*)d_in[2];
    const float* Wq  = (const float*)d_in[3];
    const float* bq  = (const float*)d_in[4];
    const float* wg  = (const float*)d_in[5];
    const float* bg  = (const float*)d_in[6];
    float* out = (float*)d_out;

    char* ws = (char*)d_ws;
    double* qp64  = (double*)ws;  ws += (size_t)ROWS * DD * 8;        // 16 MB
    double* q264  = (double*)ws;  ws += (size_t)ROWS * 8;
    double* g64   = (double*)ws;  ws += (size_t)ROWS * 8;
    double* c2c64 = (double*)ws;  ws += (size_t)BB * NN * 8;
    double* c2m64 = (double*)ws;  ws += (size_t)BB * NN * 8;
    unsigned short* qpb  = (unsigned short*)ws; ws += (size_t)ROWS * DD * 2;    // 4 MB
    unsigned short* ctxb = (unsigned short*)ws; ws += (size_t)BB * NN * DD * 2; // 8 MB
    unsigned short* memb = (unsigned short*)ws; ws += (size_t)BB * NN * DD * 2; // 8 MB
    float*  q232  = (float*)ws;   ws += (size_t)ROWS * 4;
    float*  g32   = (float*)ws;   ws += (size_t)ROWS * 4;
    float*  c2c32 = (float*)ws;   ws += (size_t)BB * NN * 4;
    float*  c2m32 = (float*)ws;   ws += (size_t)BB * NN * 4;
    float*  pvals = (float*)ws;   ws += (size_t)ROWS * PVSTRIDE * 4;  // 5.25 MB
    int*    pidx  = (int*)ws;     ws += (size_t)ROWS * PVSTRIDE * 4;  // 5.25 MB
    int*    cand  = (int*)ws;     ws += (size_t)ROWS * NCAND * 4;

    k_proj64<<<dim3(ROWS/64, DD/64), 256, 0, stream>>>(q, Wq, bq, qp64, qpb);
    k_prep_cm<<<(BB*NN)/4, 256, 0, stream>>>(ctx, ctxb, c2c64, c2c32);
    k_prep_cm<<<(BB*NN)/4, 256, 0, stream>>>(mem, memb, c2m64, c2m32);
    k_rownorm_d<<<ROWS/4, 256, 0, stream>>>(qp64, q264, q232);
    k_gate<<<ROWS/4, 256, 0, stream>>>(q, wg, bg, g64, g32);
    k_dist_mfma<<<dim3(ROWS/BM, NN/BN), 256, 0, stream>>>(
        qpb, ctxb, memb, q232, g32, c2c32, c2m32, pvals, pidx);
    k_abl_kloop<<<dim3(ROWS/BM, NN/BN), 256, 0, stream>>>(qpb, ctxb, memb);
    k_merge16<<<ROWS/4, 256, 0, stream>>>(pvals, pidx, cand);
    k_rescore<<<ROWS, 64, 0, stream>>>(qp64, ctx, mem, q264, g64,
                                       c2c64, c2m64, cand, out);
}

// Round 6
// 462.261 us; speedup vs baseline: 2.0939x; 2.0939x over previous
//
#include <hip/hip_runtime.h>
#include <hip/hip_fp16.h>
#include <math.h>

#define BB 4
#define SS 2048
#define NN 4096
#define DD 256
#define ROWS (BB*SS)        // 8192
#define TOPN 5
#define BM 128
#define BN 128
#define BK 64
#define NCAND 16

typedef short bf16x8 __attribute__((ext_vector_type(8)));
typedef float f32x4  __attribute__((ext_vector_type(4)));
typedef unsigned short u16x4 __attribute__((ext_vector_type(4)));
typedef unsigned short u16x8 __attribute__((ext_vector_type(8)));

__device__ inline unsigned short f2bf(float f) {
    unsigned int u = __float_as_uint(f);
    unsigned int r = u + 0x7fffu + ((u >> 16) & 1u);   // RNE
    return (unsigned short)(r >> 16);
}

// HBM -> LDS direct, 16 B per lane. LDS dest is wave-uniform base + lane*16.
__device__ inline void gload_lds16(const void* g, void* l) {
    __builtin_amdgcn_global_load_lds(
        (const __attribute__((address_space(1))) unsigned int*)g,
        (__attribute__((address_space(3))) unsigned int*)l, 16, 0, 0);
}

// sorted-5 insert on unsigned keys (fp16 bits: monotone for vals >= 0),
// strict < keeps earlier (smaller col) on ties
__device__ inline void ins5u(unsigned v, int gi,
                             unsigned& b0, unsigned& b1, unsigned& b2,
                             unsigned& b3, unsigned& b4,
                             int& i0, int& i1, int& i2, int& i3, int& i4) {
    if (v < b4) {
        if (v < b3) { b4 = b3; i4 = i3;
            if (v < b2) { b3 = b2; i3 = i2;
                if (v < b1) { b2 = b1; i2 = i1;
                    if (v < b0) { b1 = b0; i1 = i0; b0 = v; i0 = gi; }
                    else        { b1 = v;  i1 = gi; }
                } else { b2 = v; i2 = gi; }
            } else { b3 = v; i3 = gi; }
        } else { b4 = v; i4 = gi; }
    }
}

// ---------------- K1: qp = q @ Wq^T + bq, fp64 accumulate; writes fp64+bf16
__global__ __launch_bounds__(256) void k_proj64(
    const float* __restrict__ q, const float* __restrict__ Wq,
    const float* __restrict__ bq, double* __restrict__ qp64,
    unsigned short* __restrict__ qpb)
{
    __shared__ float As[64][65];
    __shared__ float Bs[64][65];
    const int rowbase = blockIdx.x * 64;
    const int ebase   = blockIdx.y * 64;
    const int t  = threadIdx.x;
    const int tx = t & 15;
    const int ty = t >> 4;

    double acc[4][4];
    #pragma unroll
    for (int i = 0; i < 4; ++i)
        #pragma unroll
        for (int j = 0; j < 4; ++j) acc[i][j] = 0.0;

    for (int k0 = 0; k0 < DD; k0 += 64) {
        #pragma unroll
        for (int i = 0; i < 4; ++i) {
            int r = ty + (i << 4);
            float4 va = *(const float4*)(q  + (size_t)(rowbase + r) * DD + k0 + (tx << 2));
            As[(tx<<2)+0][r] = va.x; As[(tx<<2)+1][r] = va.y;
            As[(tx<<2)+2][r] = va.z; As[(tx<<2)+3][r] = va.w;
            float4 vb = *(const float4*)(Wq + (size_t)(ebase + r) * DD + k0 + (tx << 2));
            Bs[(tx<<2)+0][r] = vb.x; Bs[(tx<<2)+1][r] = vb.y;
            Bs[(tx<<2)+2][r] = vb.z; Bs[(tx<<2)+3][r] = vb.w;
        }
        __syncthreads();
        #pragma unroll 4
        for (int kk = 0; kk < 64; ++kk) {
            double a[4], bb[4];
            #pragma unroll
            for (int i = 0; i < 4; ++i) a[i]  = (double)As[kk][(ty<<2)+i];
            #pragma unroll
            for (int j = 0; j < 4; ++j) bb[j] = (double)Bs[kk][(tx<<2)+j];
            #pragma unroll
            for (int i = 0; i < 4; ++i)
                #pragma unroll
                for (int j = 0; j < 4; ++j)
                    acc[i][j] = fma(a[i], bb[j], acc[i][j]);
        }
        __syncthreads();
    }
    #pragma unroll
    for (int i = 0; i < 4; ++i) {
        int row = rowbase + (ty << 2) + i;
        #pragma unroll
        for (int j = 0; j < 4; ++j) {
            int e = ebase + (tx << 2) + j;
            double r = acc[i][j] + (double)bq[e];
            qp64[(size_t)row * DD + e] = r;
            qpb[(size_t)row * DD + e] = f2bf((float)r);
        }
    }
}

// ------- prep ctx/mem: bf16 convert + fp64/fp32 rownorm in ONE pass -------
__global__ __launch_bounds__(256) void k_prep_cm(
    const float* __restrict__ x, unsigned short* __restrict__ xb,
    double* __restrict__ n64, float* __restrict__ n32)
{
    int row  = blockIdx.x * 4 + (threadIdx.x >> 6);
    int lane = threadIdx.x & 63;
    float4 v = *(const float4*)(x + (size_t)row * DD + (lane << 2));
    u16x4 o;
    o[0] = f2bf(v.x); o[1] = f2bf(v.y); o[2] = f2bf(v.z); o[3] = f2bf(v.w);
    *(u16x4*)(xb + (size_t)row * DD + (lane << 2)) = o;
    double s = (double)v.x*(double)v.x + (double)v.y*(double)v.y
             + (double)v.z*(double)v.z + (double)v.w*(double)v.w;
    #pragma unroll
    for (int off = 32; off; off >>= 1) s += __shfl_xor(s, off);
    if (lane == 0) { n64[row] = s; n32[row] = (float)s; }
}

// ------------- rownorm (double input): sum(x^2) in fp64, 1 wave/row -------
__global__ __launch_bounds__(256) void k_rownorm_d(
    const double* __restrict__ x, double* __restrict__ o64,
    float* __restrict__ o32)
{
    int row  = blockIdx.x * 4 + (threadIdx.x >> 6);
    int lane = threadIdx.x & 63;
    const double* p = x + (size_t)row * DD + (lane << 2);
    double s = p[0]*p[0] + p[1]*p[1] + p[2]*p[2] + p[3]*p[3];
    #pragma unroll
    for (int off = 32; off; off >>= 1) s += __shfl_xor(s, off);
    if (lane == 0) { o64[row] = s; o32[row] = (float)s; }
}

// ------------- gate: sigmoid(q . wg + bg) in fp64, 1 wave/row -------------
__global__ __launch_bounds__(256) void k_gate(
    const float* __restrict__ q, const float* __restrict__ wg,
    const float* __restrict__ bg, double* __restrict__ g64,
    float* __restrict__ g32)
{
    int row  = blockIdx.x * 4 + (threadIdx.x >> 6);
    int lane = threadIdx.x & 63;
    float4 v = *(const float4*)(q  + (size_t)row * DD + (lane << 2));
    float4 w = *(const float4*)(wg + (lane << 2));
    double s = (double)v.x*(double)w.x + (double)v.y*(double)w.y
             + (double)v.z*(double)w.z + (double)v.w*(double)w.w;
    #pragma unroll
    for (int off = 32; off; off >>= 1) s += __shfl_xor(s, off);
    if (lane == 0) {
        double g = 1.0 / (1.0 + exp(-(s + (double)bg[0])));
        g64[row] = g; g32[row] = (float)g;
    }
}

// ---------------- K3: bf16 MFMA distance GEMM -> fp16 dist matrix ----------
// Proven 32us K-loop (m97 staging). Trivial epilogue: gated dist -> fp16 store.
__global__ __launch_bounds__(256, 1) void k_dist_mfma(
    const unsigned short* __restrict__ qpb,
    const unsigned short* __restrict__ ctxb,
    const unsigned short* __restrict__ memb,
    const float* __restrict__ q2, const float* __restrict__ gate,
    const float* __restrict__ c2c, const float* __restrict__ c2m,
    unsigned short* __restrict__ distq)
{
    __shared__ __attribute__((aligned(16))) char smem[49152];
    const int tid  = threadIdx.x;
    const int lane = tid & 63;
    const int wid  = tid >> 6;
    const int wr   = wid >> 1;       // wave row (0/1) -> 64-row half
    const int wc   = wid & 1;        // wave col (0/1) -> 64-col half
    const int rowbase = blockIdx.x * BM;
    const int colbase = blockIdx.y * BN;
    const int b = rowbase / SS;
    const unsigned short* cb  = ctxb + (size_t)b * NN * DD;
    const unsigned short* mbp = memb + (size_t)b * NN * DD;

    f32x4 accC[4][4], accM[4][4];
    f32x4 zz = {0.f, 0.f, 0.f, 0.f};
    #pragma unroll
    for (int i = 0; i < 4; ++i)
        #pragma unroll
        for (int j = 0; j < 4; ++j) { accC[i][j] = zz; accM[i][j] = zz; }

    for (int t = 0; t < DD / BK; ++t) {
        const int k0 = t * BK;
        __syncthreads();   // previous consume done
        #pragma unroll
        for (int i = 0; i < 4; ++i) {
            int s = i * 256 + tid;
            int r = s >> 3, c = s & 7;
            const unsigned short* ga = qpb + (size_t)(rowbase + r) * DD + k0 + c * 8;
            const unsigned short* gc = cb  + (size_t)(colbase + r) * DD + k0 + c * 8;
            const unsigned short* gm = mbp + (size_t)(colbase + r) * DD + k0 + c * 8;
            char* la = smem +         i * 4096 + wid * 1024;   // wave-uniform
            char* lc = smem + 16384 + i * 4096 + wid * 1024;
            char* lm = smem + 32768 + i * 4096 + wid * 1024;
            gload_lds16(ga, la);
            gload_lds16(gc, lc);
            gload_lds16(gm, lm);
        }
        __syncthreads();   // stage visible
        #pragma unroll
        for (int ks = 0; ks < 2; ++ks) {
            bf16x8 af[4], bcf[4], bmf[4];
            const int koff = (ks * 4 + (lane >> 4)) * 16;   // byte offset in row
            #pragma unroll
            for (int f = 0; f < 4; ++f) {
                int arow = wr * 64 + f * 16 + (lane & 15);
                af[f] = *(const bf16x8*)(smem + arow * 128 + koff);
                int brow = wc * 64 + f * 16 + (lane & 15);
                bcf[f] = *(const bf16x8*)(smem + 16384 + brow * 128 + koff);
                bmf[f] = *(const bf16x8*)(smem + 32768 + brow * 128 + koff);
            }
            #pragma unroll
            for (int mf = 0; mf < 4; ++mf)
                #pragma unroll
                for (int nf = 0; nf < 4; ++nf) {
                    accC[mf][nf] = __builtin_amdgcn_mfma_f32_16x16x32_bf16(
                        af[mf], bcf[nf], accC[mf][nf], 0, 0, 0);
                    accM[mf][nf] = __builtin_amdgcn_mfma_f32_16x16x32_bf16(
                        af[mf], bmf[nf], accM[mf][nf], 0, 0, 0);
                }
        }
    }

    // per-lane row/col metadata (C/D map: row=(lane>>4)*4+reg, col=lane&15)
    float q2r[4][4], gr[4][4];
    #pragma unroll
    for (int mf = 0; mf < 4; ++mf)
        #pragma unroll
        for (int rg = 0; rg < 4; ++rg) {
            int r = rowbase + wr * 64 + mf * 16 + ((lane >> 4) << 2) + rg;
            q2r[mf][rg] = q2[r];
            gr[mf][rg]  = gate[r];
        }
    float ccv[4], cmv[4];
    #pragma unroll
    for (int nf = 0; nf < 4; ++nf) {
        int c = colbase + wc * 64 + nf * 16 + (lane & 15);
        ccv[nf] = c2c[b * NN + c];
        cmv[nf] = c2m[b * NN + c];
    }

    #pragma unroll
    for (int mf = 0; mf < 4; ++mf)
        #pragma unroll
        for (int rg = 0; rg < 4; ++rg) {
            size_t rb = (size_t)(rowbase + wr * 64 + mf * 16
                                 + ((lane >> 4) << 2) + rg) * NN;
            float g = gr[mf][rg];
            #pragma unroll
            for (int nf = 0; nf < 4; ++nf) {
                int col = colbase + wc * 64 + nf * 16 + (lane & 15);
                float dc = sqrtf(fmaxf(q2r[mf][rg] + ccv[nf]
                                       - 2.0f * accC[mf][nf][rg], 0.f));
                float dm = sqrtf(fmaxf(q2r[mf][rg] + cmv[nf]
                                       - 2.0f * accM[mf][nf][rg], 0.f));
                float d = g * dc + (1.f - g) * dm;
                distq[rb + col] = __half_as_ushort(__float2half(d));
            }
        }
}

// ---------------- K4: per-row top-16 candidates from fp16 dist row --------
// One wave per row. fp16 bits compared as unsigned (monotone for vals >= 0).
__global__ __launch_bounds__(256) void k_filter(
    const unsigned short* __restrict__ distq, int* __restrict__ cand)
{
    int row  = blockIdx.x * 4 + (threadIdx.x >> 6);
    int lane = threadIdx.x & 63;
    const unsigned short* dr = distq + (size_t)row * NN;

    unsigned b0 = 0xFFFFu, b1 = 0xFFFFu, b2 = 0xFFFFu, b3 = 0xFFFFu, b4 = 0xFFFFu;
    int i0 = 0x7fffffff, i1 = 0x7fffffff, i2 = 0x7fffffff, i3 = 0x7fffffff, i4 = 0x7fffffff;

    #pragma unroll
    for (int ch = 0; ch < 8; ++ch) {
        u16x8 u = *(const u16x8*)(dr + ch * 512 + lane * 8);
        int base = ch * 512 + lane * 8;
        #pragma unroll
        for (int j = 0; j < 8; ++j)
            ins5u((unsigned)u[j], base + j, b0, b1, b2, b3, b4, i0, i1, i2, i3, i4);
    }

    #pragma unroll
    for (int r = 0; r < NCAND; ++r) {
        unsigned mv = b0; int mi = i0;
        #pragma unroll
        for (int off = 1; off < 64; off <<= 1) {
            unsigned ov = __shfl_xor(mv, off);
            int      oi = __shfl_xor(mi, off);
            if (ov < mv || (ov == mv && oi < mi)) { mv = ov; mi = oi; }
        }
        if (b0 == mv && i0 == mi) {   // winner pops (indices unique per row)
            b0 = b1; i0 = i1; b1 = b2; i1 = i2; b2 = b3; i2 = i3;
            b3 = b4; i3 = i4; b4 = 0xFFFFu; i4 = 0x7fffffff;
        }
        if (lane == 0) cand[(size_t)row * NCAND + r] = mi;
    }
}

// ---------------- K5: fp64 exact rescore of 16 candidates, final top-5 ----
__global__ __launch_bounds__(64) void k_rescore(
    const double* __restrict__ qp64, const float* __restrict__ ctx,
    const float* __restrict__ mem, const double* __restrict__ q2,
    const double* __restrict__ gate, const double* __restrict__ c2c,
    const double* __restrict__ c2m, const int* __restrict__ cand,
    float* __restrict__ out)
{
    __shared__ double sval[NCAND];
    __shared__ int    sidx[NCAND];
    const int row  = blockIdx.x;
    const int lane = threadIdx.x;
    const int b = row / SS;

    const double* qr = qp64 + (size_t)row * DD + (lane << 2);
    double a0 = qr[0], a1 = qr[1], a2 = qr[2], a3 = qr[3];
    double q2r = q2[row], g = gate[row];

    for (int c = 0; c < NCAND; ++c) {
        int idx = cand[(size_t)row * NCAND + c];
        const float4 vc = *(const float4*)(ctx + ((size_t)b * NN + idx) * DD + (lane << 2));
        const float4 vm = *(const float4*)(mem + ((size_t)b * NN + idx) * DD + (lane << 2));
        double sc = a0*(double)vc.x + a1*(double)vc.y + a2*(double)vc.z + a3*(double)vc.w;
        double sm = a0*(double)vm.x + a1*(double)vm.y + a2*(double)vm.z + a3*(double)vm.w;
        #pragma unroll
        for (int off = 32; off; off >>= 1) {
            sc += __shfl_xor(sc, off);
            sm += __shfl_xor(sm, off);
        }
        if (lane == 0) {
            double dc = sqrt(fmax(q2r + c2c[(size_t)b * NN + idx] - 2.0 * sc, 0.0));
            double dm = sqrt(fmax(q2r + c2m[(size_t)b * NN + idx] - 2.0 * sm, 0.0));
            sval[c] = g * dc + (1.0 - g) * dm;
            sidx[c] = idx;
        }
    }
    __syncthreads();
    if (lane == 0) {
        #pragma unroll
        for (int r = 0; r < TOPN; ++r) {
            double bv = sval[0]; int bi = sidx[0]; int bp = 0;
            for (int c = 1; c < NCAND; ++c) {
                double v = sval[c]; int ii = sidx[c];
                if (v < bv || (v == bv && ii < bi)) { bv = v; bi = ii; bp = c; }
            }
            sval[bp] = INFINITY; sidx[bp] = 0x7fffffff;
            out[(size_t)row * TOPN + r] = (float)bv;
            out[(size_t)ROWS * TOPN + (size_t)row * TOPN + r] = (float)bi;
        }
    }
}

extern "C" void kernel_launch(void* const* d_in, const int* in_sizes, int n_in,
                              void* d_out, int out_size, void* d_ws, size_t ws_size,
                              hipStream_t stream)
{
    const float* q   = (const float*)d_in[0];
    const float* ctx = (const float*)d_in[1];
    const float* mem = (const float*)d_in[2];
    const float* Wq  = (const float*)d_in[3];
    const float* bq  = (const float*)d_in[4];
    const float* wg  = (const float*)d_in[5];
    const float* bg  = (const float*)d_in[6];
    float* out = (float*)d_out;

    char* ws = (char*)d_ws;
    double* qp64  = (double*)ws;  ws += (size_t)ROWS * DD * 8;        // 16 MB
    double* q264  = (double*)ws;  ws += (size_t)ROWS * 8;
    double* g64   = (double*)ws;  ws += (size_t)ROWS * 8;
    double* c2c64 = (double*)ws;  ws += (size_t)BB * NN * 8;
    double* c2m64 = (double*)ws;  ws += (size_t)BB * NN * 8;
    unsigned short* qpb  = (unsigned short*)ws; ws += (size_t)ROWS * DD * 2;    // 4 MB
    unsigned short* ctxb = (unsigned short*)ws; ws += (size_t)BB * NN * DD * 2; // 8 MB
    unsigned short* memb = (unsigned short*)ws; ws += (size_t)BB * NN * DD * 2; // 8 MB
    float*  q232  = (float*)ws;   ws += (size_t)ROWS * 4;
    float*  g32   = (float*)ws;   ws += (size_t)ROWS * 4;
    float*  c2c32 = (float*)ws;   ws += (size_t)BB * NN * 4;
    float*  c2m32 = (float*)ws;   ws += (size_t)BB * NN * 4;
    unsigned short* distq = (unsigned short*)ws; ws += (size_t)ROWS * NN * 2;   // 67 MB
    int*    cand  = (int*)ws;     ws += (size_t)ROWS * NCAND * 4;

    k_proj64<<<dim3(ROWS/64, DD/64), 256, 0, stream>>>(q, Wq, bq, qp64, qpb);
    k_prep_cm<<<(BB*NN)/4, 256, 0, stream>>>(ctx, ctxb, c2c64, c2c32);
    k_prep_cm<<<(BB*NN)/4, 256, 0, stream>>>(mem, memb, c2m64, c2m32);
    k_rownorm_d<<<ROWS/4, 256, 0, stream>>>(qp64, q264, q232);
    k_gate<<<ROWS/4, 256, 0, stream>>>(q, wg, bg, g64, g32);
    k_dist_mfma<<<dim3(ROWS/BM, NN/BN), 256, 0, stream>>>(
        qpb, ctxb, memb, q232, g32, c2c32, c2m32, distq);
    k_filter<<<ROWS/4, 256, 0, stream>>>(distq, cand);
    k_rescore<<<ROWS, 64, 0, stream>>>(qp64, ctx, mem, q264, g64,
                                       c2c64, c2m64, cand, out);
}

// Round 7
// 267.733 us; speedup vs baseline: 3.6154x; 1.7266x over previous
//
#include <hip/hip_runtime.h>
#include <hip/hip_fp16.h>
#include <math.h>

#define BB 4
#define SS 2048
#define NN 4096
#define DD 256
#define ROWS (BB*SS)        // 8192
#define TOPN 5
#define BM 128
#define BN 128
#define BK 64
#define NCAND 16

typedef short bf16x8 __attribute__((ext_vector_type(8)));
typedef float f32x4  __attribute__((ext_vector_type(4)));
typedef unsigned short u16x4 __attribute__((ext_vector_type(4)));

__device__ inline unsigned short f2bf(float f) {
    unsigned int u = __float_as_uint(f);
    unsigned int r = u + 0x7fffu + ((u >> 16) & 1u);   // RNE
    return (unsigned short)(r >> 16);
}

// HBM -> LDS direct, 16 B per lane. LDS dest is wave-uniform base + lane*16.
__device__ inline void gload_lds16(const void* g, void* l) {
    __builtin_amdgcn_global_load_lds(
        (const __attribute__((address_space(1))) unsigned int*)g,
        (__attribute__((address_space(3))) unsigned int*)l, 16, 0, 0);
}

// sorted-5 insert as MACRO on named scalars (NO reference-param helper:
// refs defeat mem2reg -> state lands in scratch; round-6 k_filter showed
// VGPR=16 + 58MB scratch writes + 10x slowdown from exactly this).
#define INS5U(vv, gg)                                                   \
    do {                                                                \
        unsigned _v = (vv); int _g = (gg);                              \
        if (_v < B4) {                                                  \
            if (_v < B3) { B4 = B3; I4 = I3;                            \
                if (_v < B2) { B3 = B2; I3 = I2;                        \
                    if (_v < B1) { B2 = B1; I2 = I1;                    \
                        if (_v < B0) { B1 = B0; I1 = I0; B0 = _v; I0 = _g; } \
                        else         { B1 = _v; I1 = _g; }              \
                    } else { B2 = _v; I2 = _g; }                        \
                } else { B3 = _v; I3 = _g; }                            \
            } else { B4 = _v; I4 = _g; }                                \
        }                                                               \
    } while (0)

// ---------------- K1: qp = q @ Wq^T + bq, fp64 accumulate; writes fp64+bf16
__global__ __launch_bounds__(256) void k_proj64(
    const float* __restrict__ q, const float* __restrict__ Wq,
    const float* __restrict__ bq, double* __restrict__ qp64,
    unsigned short* __restrict__ qpb)
{
    __shared__ float As[64][65];
    __shared__ float Bs[64][65];
    const int rowbase = blockIdx.x * 64;
    const int ebase   = blockIdx.y * 64;
    const int t  = threadIdx.x;
    const int tx = t & 15;
    const int ty = t >> 4;

    double acc[4][4];
    #pragma unroll
    for (int i = 0; i < 4; ++i)
        #pragma unroll
        for (int j = 0; j < 4; ++j) acc[i][j] = 0.0;

    for (int k0 = 0; k0 < DD; k0 += 64) {
        #pragma unroll
        for (int i = 0; i < 4; ++i) {
            int r = ty + (i << 4);
            float4 va = *(const float4*)(q  + (size_t)(rowbase + r) * DD + k0 + (tx << 2));
            As[(tx<<2)+0][r] = va.x; As[(tx<<2)+1][r] = va.y;
            As[(tx<<2)+2][r] = va.z; As[(tx<<2)+3][r] = va.w;
            float4 vb = *(const float4*)(Wq + (size_t)(ebase + r) * DD + k0 + (tx << 2));
            Bs[(tx<<2)+0][r] = vb.x; Bs[(tx<<2)+1][r] = vb.y;
            Bs[(tx<<2)+2][r] = vb.z; Bs[(tx<<2)+3][r] = vb.w;
        }
        __syncthreads();
        #pragma unroll 4
        for (int kk = 0; kk < 64; ++kk) {
            double a[4], bb[4];
            #pragma unroll
            for (int i = 0; i < 4; ++i) a[i]  = (double)As[kk][(ty<<2)+i];
            #pragma unroll
            for (int j = 0; j < 4; ++j) bb[j] = (double)Bs[kk][(tx<<2)+j];
            #pragma unroll
            for (int i = 0; i < 4; ++i)
                #pragma unroll
                for (int j = 0; j < 4; ++j)
                    acc[i][j] = fma(a[i], bb[j], acc[i][j]);
        }
        __syncthreads();
    }
    #pragma unroll
    for (int i = 0; i < 4; ++i) {
        int row = rowbase + (ty << 2) + i;
        #pragma unroll
        for (int j = 0; j < 4; ++j) {
            int e = ebase + (tx << 2) + j;
            double r = acc[i][j] + (double)bq[e];
            qp64[(size_t)row * DD + e] = r;
            qpb[(size_t)row * DD + e] = f2bf((float)r);
        }
    }
}

// ------- prep ctx/mem: bf16 convert + fp64/fp32 rownorm in ONE pass -------
__global__ __launch_bounds__(256) void k_prep_cm(
    const float* __restrict__ x, unsigned short* __restrict__ xb,
    double* __restrict__ n64, float* __restrict__ n32)
{
    int row  = blockIdx.x * 4 + (threadIdx.x >> 6);
    int lane = threadIdx.x & 63;
    float4 v = *(const float4*)(x + (size_t)row * DD + (lane << 2));
    u16x4 o;
    o[0] = f2bf(v.x); o[1] = f2bf(v.y); o[2] = f2bf(v.z); o[3] = f2bf(v.w);
    *(u16x4*)(xb + (size_t)row * DD + (lane << 2)) = o;
    double s = (double)v.x*(double)v.x + (double)v.y*(double)v.y
             + (double)v.z*(double)v.z + (double)v.w*(double)v.w;
    #pragma unroll
    for (int off = 32; off; off >>= 1) s += __shfl_xor(s, off);
    if (lane == 0) { n64[row] = s; n32[row] = (float)s; }
}

// ------------- rownorm (double input): sum(x^2) in fp64, 1 wave/row -------
__global__ __launch_bounds__(256) void k_rownorm_d(
    const double* __restrict__ x, double* __restrict__ o64,
    float* __restrict__ o32)
{
    int row  = blockIdx.x * 4 + (threadIdx.x >> 6);
    int lane = threadIdx.x & 63;
    const double* p = x + (size_t)row * DD + (lane << 2);
    double s = p[0]*p[0] + p[1]*p[1] + p[2]*p[2] + p[3]*p[3];
    #pragma unroll
    for (int off = 32; off; off >>= 1) s += __shfl_xor(s, off);
    if (lane == 0) { o64[row] = s; o32[row] = (float)s; }
}

// ------------- gate: sigmoid(q . wg + bg) in fp64, 1 wave/row -------------
__global__ __launch_bounds__(256) void k_gate(
    const float* __restrict__ q, const float* __restrict__ wg,
    const float* __restrict__ bg, double* __restrict__ g64,
    float* __restrict__ g32)
{
    int row  = blockIdx.x * 4 + (threadIdx.x >> 6);
    int lane = threadIdx.x & 63;
    float4 v = *(const float4*)(q  + (size_t)row * DD + (lane << 2));
    float4 w = *(const float4*)(wg + (lane << 2));
    double s = (double)v.x*(double)w.x + (double)v.y*(double)w.y
             + (double)v.z*(double)w.z + (double)v.w*(double)w.w;
    #pragma unroll
    for (int off = 32; off; off >>= 1) s += __shfl_xor(s, off);
    if (lane == 0) {
        double g = 1.0 / (1.0 + exp(-(s + (double)bg[0])));
        g64[row] = g; g32[row] = (float)g;
    }
}

// ---------------- K3: bf16 MFMA distance GEMM -> fp16 dist matrix ----------
// Proven 32us K-loop (m97 staging). Trivial epilogue: gated dist -> fp16 store.
__global__ __launch_bounds__(256, 1) void k_dist_mfma(
    const unsigned short* __restrict__ qpb,
    const unsigned short* __restrict__ ctxb,
    const unsigned short* __restrict__ memb,
    const float* __restrict__ q2, const float* __restrict__ gate,
    const float* __restrict__ c2c, const float* __restrict__ c2m,
    unsigned short* __restrict__ distq)
{
    __shared__ __attribute__((aligned(16))) char smem[49152];
    const int tid  = threadIdx.x;
    const int lane = tid & 63;
    const int wid  = tid >> 6;
    const int wr   = wid >> 1;       // wave row (0/1) -> 64-row half
    const int wc   = wid & 1;        // wave col (0/1) -> 64-col half
    const int rowbase = blockIdx.x * BM;
    const int colbase = blockIdx.y * BN;
    const int b = rowbase / SS;
    const unsigned short* cb  = ctxb + (size_t)b * NN * DD;
    const unsigned short* mbp = memb + (size_t)b * NN * DD;

    f32x4 accC[4][4], accM[4][4];
    f32x4 zz = {0.f, 0.f, 0.f, 0.f};
    #pragma unroll
    for (int i = 0; i < 4; ++i)
        #pragma unroll
        for (int j = 0; j < 4; ++j) { accC[i][j] = zz; accM[i][j] = zz; }

    for (int t = 0; t < DD / BK; ++t) {
        const int k0 = t * BK;
        __syncthreads();   // previous consume done
        #pragma unroll
        for (int i = 0; i < 4; ++i) {
            int s = i * 256 + tid;
            int r = s >> 3, c = s & 7;
            const unsigned short* ga = qpb + (size_t)(rowbase + r) * DD + k0 + c * 8;
            const unsigned short* gc = cb  + (size_t)(colbase + r) * DD + k0 + c * 8;
            const unsigned short* gm = mbp + (size_t)(colbase + r) * DD + k0 + c * 8;
            char* la = smem +         i * 4096 + wid * 1024;   // wave-uniform
            char* lc = smem + 16384 + i * 4096 + wid * 1024;
            char* lm = smem + 32768 + i * 4096 + wid * 1024;
            gload_lds16(ga, la);
            gload_lds16(gc, lc);
            gload_lds16(gm, lm);
        }
        __syncthreads();   // stage visible
        #pragma unroll
        for (int ks = 0; ks < 2; ++ks) {
            bf16x8 af[4], bcf[4], bmf[4];
            const int koff = (ks * 4 + (lane >> 4)) * 16;   // byte offset in row
            #pragma unroll
            for (int f = 0; f < 4; ++f) {
                int arow = wr * 64 + f * 16 + (lane & 15);
                af[f] = *(const bf16x8*)(smem + arow * 128 + koff);
                int brow = wc * 64 + f * 16 + (lane & 15);
                bcf[f] = *(const bf16x8*)(smem + 16384 + brow * 128 + koff);
                bmf[f] = *(const bf16x8*)(smem + 32768 + brow * 128 + koff);
            }
            #pragma unroll
            for (int mf = 0; mf < 4; ++mf)
                #pragma unroll
                for (int nf = 0; nf < 4; ++nf) {
                    accC[mf][nf] = __builtin_amdgcn_mfma_f32_16x16x32_bf16(
                        af[mf], bcf[nf], accC[mf][nf], 0, 0, 0);
                    accM[mf][nf] = __builtin_amdgcn_mfma_f32_16x16x32_bf16(
                        af[mf], bmf[nf], accM[mf][nf], 0, 0, 0);
                }
        }
    }

    // per-lane row/col metadata (C/D map: row=(lane>>4)*4+reg, col=lane&15)
    float q2r[4][4], gr[4][4];
    #pragma unroll
    for (int mf = 0; mf < 4; ++mf)
        #pragma unroll
        for (int rg = 0; rg < 4; ++rg) {
            int r = rowbase + wr * 64 + mf * 16 + ((lane >> 4) << 2) + rg;
            q2r[mf][rg] = q2[r];
            gr[mf][rg]  = gate[r];
        }
    float ccv[4], cmv[4];
    #pragma unroll
    for (int nf = 0; nf < 4; ++nf) {
        int c = colbase + wc * 64 + nf * 16 + (lane & 15);
        ccv[nf] = c2c[b * NN + c];
        cmv[nf] = c2m[b * NN + c];
    }

    #pragma unroll
    for (int mf = 0; mf < 4; ++mf)
        #pragma unroll
        for (int rg = 0; rg < 4; ++rg) {
            size_t rb = (size_t)(rowbase + wr * 64 + mf * 16
                                 + ((lane >> 4) << 2) + rg) * NN;
            float g = gr[mf][rg];
            #pragma unroll
            for (int nf = 0; nf < 4; ++nf) {
                int col = colbase + wc * 64 + nf * 16 + (lane & 15);
                float dc = sqrtf(fmaxf(q2r[mf][rg] + ccv[nf]
                                       - 2.0f * accC[mf][nf][rg], 0.f));
                float dm = sqrtf(fmaxf(q2r[mf][rg] + cmv[nf]
                                       - 2.0f * accM[mf][nf][rg], 0.f));
                float d = g * dc + (1.f - g) * dm;
                distq[rb + col] = __half_as_ushort(__float2half(d));
            }
        }
}

// ---------------- K4: per-row top-16 candidates from fp16 dist row --------
// One wave per row. fp16 bits compared as unsigned (monotone for vals >= 0).
// Sorted-5 state in NAMED SCALARS via macro; uint4 loads + bit extraction.
__global__ __launch_bounds__(256) void k_filter(
    const unsigned* __restrict__ distq, int* __restrict__ cand)
{
    int row  = blockIdx.x * 4 + (threadIdx.x >> 6);
    int lane = threadIdx.x & 63;
    const unsigned* dr = distq + (size_t)row * (NN / 2);   // 2 fp16 per uint

    unsigned B0 = 0xFFFFu, B1 = 0xFFFFu, B2 = 0xFFFFu, B3 = 0xFFFFu, B4 = 0xFFFFu;
    int I0 = 0x7fffffff, I1 = 0x7fffffff, I2 = 0x7fffffff, I3 = 0x7fffffff, I4 = 0x7fffffff;

    #pragma unroll
    for (int ch = 0; ch < 8; ++ch) {
        uint4 w = *(const uint4*)(dr + ch * 256 + lane * 4);
        int base = ch * 512 + lane * 8;
        INS5U(w.x & 0xFFFFu, base + 0);
        INS5U(w.x >> 16,     base + 1);
        INS5U(w.y & 0xFFFFu, base + 2);
        INS5U(w.y >> 16,     base + 3);
        INS5U(w.z & 0xFFFFu, base + 4);
        INS5U(w.z >> 16,     base + 5);
        INS5U(w.w & 0xFFFFu, base + 6);
        INS5U(w.w >> 16,     base + 7);
    }

    #pragma unroll
    for (int r = 0; r < NCAND; ++r) {
        unsigned mv = B0; int mi = I0;
        #pragma unroll
        for (int off = 1; off < 64; off <<= 1) {
            unsigned ov = __shfl_xor(mv, off);
            int      oi = __shfl_xor(mi, off);
            if (ov < mv || (ov == mv && oi < mi)) { mv = ov; mi = oi; }
        }
        if (B0 == mv && I0 == mi) {   // winner pops (indices unique per row)
            B0 = B1; I0 = I1; B1 = B2; I1 = I2; B2 = B3; I2 = I3;
            B3 = B4; I3 = I4; B4 = 0xFFFFu; I4 = 0x7fffffff;
        }
        if (lane == 0) cand[(size_t)row * NCAND + r] = mi;
    }
}

// ---------------- K5: fp64 exact rescore of 16 candidates, final top-5 ----
__global__ __launch_bounds__(64) void k_rescore(
    const double* __restrict__ qp64, const float* __restrict__ ctx,
    const float* __restrict__ mem, const double* __restrict__ q2,
    const double* __restrict__ gate, const double* __restrict__ c2c,
    const double* __restrict__ c2m, const int* __restrict__ cand,
    float* __restrict__ out)
{
    __shared__ double sval[NCAND];
    __shared__ int    sidx[NCAND];
    const int row  = blockIdx.x;
    const int lane = threadIdx.x;
    const int b = row / SS;

    const double* qr = qp64 + (size_t)row * DD + (lane << 2);
    double a0 = qr[0], a1 = qr[1], a2 = qr[2], a3 = qr[3];
    double q2r = q2[row], g = gate[row];

    for (int c = 0; c < NCAND; ++c) {
        int idx = cand[(size_t)row * NCAND + c];
        const float4 vc = *(const float4*)(ctx + ((size_t)b * NN + idx) * DD + (lane << 2));
        const float4 vm = *(const float4*)(mem + ((size_t)b * NN + idx) * DD + (lane << 2));
        double sc = a0*(double)vc.x + a1*(double)vc.y + a2*(double)vc.z + a3*(double)vc.w;
        double sm = a0*(double)vm.x + a1*(double)vm.y + a2*(double)vm.z + a3*(double)vm.w;
        #pragma unroll
        for (int off = 32; off; off >>= 1) {
            sc += __shfl_xor(sc, off);
            sm += __shfl_xor(sm, off);
        }
        if (lane == 0) {
            double dc = sqrt(fmax(q2r + c2c[(size_t)b * NN + idx] - 2.0 * sc, 0.0));
            double dm = sqrt(fmax(q2r + c2m[(size_t)b * NN + idx] - 2.0 * sm, 0.0));
            sval[c] = g * dc + (1.0 - g) * dm;
            sidx[c] = idx;
        }
    }
    __syncthreads();
    if (lane == 0) {
        #pragma unroll
        for (int r = 0; r < TOPN; ++r) {
            double bv = sval[0]; int bi = sidx[0]; int bp = 0;
            for (int c = 1; c < NCAND; ++c) {
                double v = sval[c]; int ii = sidx[c];
                if (v < bv || (v == bv && ii < bi)) { bv = v; bi = ii; bp = c; }
            }
            sval[bp] = INFINITY; sidx[bp] = 0x7fffffff;
            out[(size_t)row * TOPN + r] = (float)bv;
            out[(size_t)ROWS * TOPN + (size_t)row * TOPN + r] = (float)bi;
        }
    }
}

extern "C" void kernel_launch(void* const* d_in, const int* in_sizes, int n_in,
                              void* d_out, int out_size, void* d_ws, size_t ws_size,
                              hipStream_t stream)
{
    const float* q   = (const float*)d_in[0];
    const float* ctx = (const float*)d_in[1];
    const float* mem = (const float*)d_in[2];
    const float* Wq  = (const float*)d_in[3];
    const float* bq  = (const float*)d_in[4];
    const float* wg  = (const float*)d_in[5];
    const float* bg  = (const float*)d_in[6];
    float* out = (float*)d_out;

    char* ws = (char*)d_ws;
    double* qp64  = (double*)ws;  ws += (size_t)ROWS * DD * 8;        // 16 MB
    double* q264  = (double*)ws;  ws += (size_t)ROWS * 8;
    double* g64   = (double*)ws;  ws += (size_t)ROWS * 8;
    double* c2c64 = (double*)ws;  ws += (size_t)BB * NN * 8;
    double* c2m64 = (double*)ws;  ws += (size_t)BB * NN * 8;
    unsigned short* qpb  = (unsigned short*)ws; ws += (size_t)ROWS * DD * 2;    // 4 MB
    unsigned short* ctxb = (unsigned short*)ws; ws += (size_t)BB * NN * DD * 2; // 8 MB
    unsigned short* memb = (unsigned short*)ws; ws += (size_t)BB * NN * DD * 2; // 8 MB
    float*  q232  = (float*)ws;   ws += (size_t)ROWS * 4;
    float*  g32   = (float*)ws;   ws += (size_t)ROWS * 4;
    float*  c2c32 = (float*)ws;   ws += (size_t)BB * NN * 4;
    float*  c2m32 = (float*)ws;   ws += (size_t)BB * NN * 4;
    unsigned short* distq = (unsigned short*)ws; ws += (size_t)ROWS * NN * 2;   // 67 MB
    int*    cand  = (int*)ws;     ws += (size_t)ROWS * NCAND * 4;

    k_proj64<<<dim3(ROWS/64, DD/64), 256, 0, stream>>>(q, Wq, bq, qp64, qpb);
    k_prep_cm<<<(BB*NN)/4, 256, 0, stream>>>(ctx, ctxb, c2c64, c2c32);
    k_prep_cm<<<(BB*NN)/4, 256, 0, stream>>>(mem, memb, c2m64, c2m32);
    k_rownorm_d<<<ROWS/4, 256, 0, stream>>>(qp64, q264, q232);
    k_gate<<<ROWS/4, 256, 0, stream>>>(q, wg, bg, g64, g32);
    k_dist_mfma<<<dim3(ROWS/BM, NN/BN), 256, 0, stream>>>(
        qpb, ctxb, memb, q232, g32, c2c32, c2m32, distq);
    k_filter<<<ROWS/4, 256, 0, stream>>>((const unsigned*)distq, cand);
    k_rescore<<<ROWS, 64, 0, stream>>>(qp64, ctx, mem, q264, g64,
                                       c2c64, c2m64, cand, out);
}